// Round 1
// 74.023 us; speedup vs baseline: 1.0361x; 1.0361x over previous
//
#include <hip/hip_runtime.h>
#include <cmath>

// Problem constants (match reference)
#define BB 4
#define NN 48
#define PP (NN * NN)   // 2304 (x,y) pairs per plane
#define TT 33
#define RR 16
#define NC 80
#define NI 5
#define NEG (-1000.0f)

#define XH 24          // x-rows per chain-DP block (x-split factor 2)
#define RS 52          // padded row stride (words) for row-major A tiles
                       // 52*4B=208B rows: 16B-aligned float4 rows; lane bank
                       // spread for xt strides (3*52=156, 156%32=28 -> all 8
                       // xt groups hit distinct bank quads)

// ---------------------------------------------------------------------------
// Kernel 0: transpose trans [B, 2304, 33] -> tpose [B, 33, 2304] so every
// hop-plane becomes a contiguous 9 KB block. LDS-tiled: coalesced float4
// reads, coalesced 64-wide writes; LDS read stride 33 words (gcd(33,32)=1,
// conflict-free).
// ---------------------------------------------------------------------------
__global__ __launch_bounds__(256) void transpose_kernel(
    const float* __restrict__ trans,   // [B, 2304, 33]
    float*       __restrict__ tpose)   // [B, 33, 2304]
{
    __shared__ float tile[64 * TT];    // 64 p x 33 t
    const int blk = blockIdx.x;        // B * 36
    const int b   = blk / 36;
    const int p0  = (blk - b * 36) * 64;

    const float4* src = (const float4*)(trans + ((size_t)b * PP + p0) * TT);
    for (int j = threadIdx.x; j < 64 * TT / 4; j += 256)
        ((float4*)tile)[j] = src[j];
    __syncthreads();

    for (int j = threadIdx.x; j < TT * 64; j += 256) {
        const int t  = j >> 6;
        const int pl = j & 63;
        tpose[((size_t)b * TT + t) * PP + p0 + pl] = tile[pl * TT + t];
    }
}

// ---------------------------------------------------------------------------
// Kernel 1: per-(b,c,xhalf) tropical chain DP.
//   v2 changes vs 75us baseline:
//   - A operands kept ROW-major ([x][k], pad 52) -> all-vector LDS reads:
//     per 4-k step: 3x ds_read_b128 (A rows) + 4x ds_read_b64 (B cols).
//     (tpose plane is already [x][k]; the old transposed H0T forced 6 scalar
//     ds_read_b32 per 2-k step = ~45% of issue slots.)
//   - x-split 2: grid 640 blocks x 24 rows. waves/CU 3.75 -> 7.5, tail
//     imbalance 2x -> 1.2x, LDS 28 KB/block.
//   Max-plus is exactly associative -> bit-identical results to v1.
// ---------------------------------------------------------------------------
__global__ __launch_bounds__(192) void chain_dp_kernel(
    const float* __restrict__ tpose,    // [B, 33, 2304]
    const int*   __restrict__ rules,    // [Nc,3]
    const float* __restrict__ weights,  // [Nc]
    float*       __restrict__ sw)       // [B,Nc,N,N]
{
    __shared__ float H0R[XH * RS];  // A of product 1, [x][k] rows, padded
    __shared__ float H1 [PP];       // B of product 1, [k][y]
    __shared__ float H2 [PP];       // B of product 2, [k][y]
    __shared__ float S1R[XH * RS];  // A of product 2, [x][k] rows, padded

    const int blk = blockIdx.x;     // b*NC*2 + c*2 + xh
    const int bc  = blk >> 1;
    const int xh  = blk & 1;
    const int b   = bc / NC;
    const int c   = bc - b * NC;
    const int x0r = xh * XH;

    const int r0 = rules[c * 3 + 0];
    const int r1 = rules[c * 3 + 1];
    const int r2 = rules[c * 3 + 2];

    const float* p0 = tpose + ((size_t)b * TT + r0) * PP + (size_t)x0r * NN;
    const float* p1 = tpose + ((size_t)b * TT + r1) * PP;
    const float* p2 = tpose + ((size_t)b * TT + r2) * PP;

    // Stage B planes (full 48x48, 576 float4 -> 3/thread) and this block's
    // 24 A rows (288 float4 -> 1-2/thread) with coalesced float4 loads.
    for (int j = threadIdx.x; j < PP / 4; j += 192) {
        ((float4*)H1)[j] = ((const float4*)p1)[j];
        ((float4*)H2)[j] = ((const float4*)p2)[j];
    }
    for (int j = threadIdx.x; j < XH * NN / 4; j += 192) {
        const int row = j / 12;          // 12 float4 per 48-wide row
        const int cw  = j - row * 12;
        *(float4*)&H0R[row * RS + cw * 4] = ((const float4*)p0)[j];
    }
    __syncthreads();

    const int yt = threadIdx.x % 24;   // 24 y-tiles of 2
    const int xt = threadIdx.x / 24;   // 8 x-tiles of 3
    const int x0 = xt * 3;
    const int y0 = yt * 2;

    // ---- product 1: S1 = H0 (x) H1 ----
    float acc[3][2];
    #pragma unroll
    for (int jx = 0; jx < 3; ++jx) { acc[jx][0] = -INFINITY; acc[jx][1] = -INFINITY; }

    #pragma unroll 4
    for (int k4 = 0; k4 < NN; k4 += 4) {
        const float4 a0 = *(const float4*)&H0R[(x0 + 0) * RS + k4];
        const float4 a1 = *(const float4*)&H0R[(x0 + 1) * RS + k4];
        const float4 a2 = *(const float4*)&H0R[(x0 + 2) * RS + k4];
        const float2 b0 = *(const float2*)&H1[(k4 + 0) * NN + y0];
        const float2 b1 = *(const float2*)&H1[(k4 + 1) * NN + y0];
        const float2 b2 = *(const float2*)&H1[(k4 + 2) * NN + y0];
        const float2 b3 = *(const float2*)&H1[(k4 + 3) * NN + y0];
        const float av[3][4] = {{a0.x, a0.y, a0.z, a0.w},
                                {a1.x, a1.y, a1.z, a1.w},
                                {a2.x, a2.y, a2.z, a2.w}};
        const float bv[4][2] = {{b0.x, b0.y}, {b1.x, b1.y},
                                {b2.x, b2.y}, {b3.x, b3.y}};
        #pragma unroll
        for (int jx = 0; jx < 3; ++jx)
            #pragma unroll
            for (int jy = 0; jy < 2; ++jy) {
                const float s0 = av[jx][0] + bv[0][jy];
                const float s1 = av[jx][1] + bv[1][jy];
                const float s2 = av[jx][2] + bv[2][jy];
                const float s3 = av[jx][3] + bv[3][jy];
                acc[jx][jy] = fmaxf(acc[jx][jy], fmaxf(s0, s1));  // v_max3
                acc[jx][jy] = fmaxf(acc[jx][jy], fmaxf(s2, s3));  // v_max3
            }
    }

    // S1R[x][k]: float2 writes, lanes step yt -> 2-word stride (<=2-way: free)
    #pragma unroll
    for (int jx = 0; jx < 3; ++jx) {
        float2 v; v.x = acc[jx][0]; v.y = acc[jx][1];
        *(float2*)&S1R[(x0 + jx) * RS + y0] = v;
    }
    __syncthreads();

    // ---- product 2: S = S1 (x) H2, fused exp*weight epilogue ----
    float acc2[3][2];
    #pragma unroll
    for (int jx = 0; jx < 3; ++jx) { acc2[jx][0] = -INFINITY; acc2[jx][1] = -INFINITY; }

    #pragma unroll 4
    for (int k4 = 0; k4 < NN; k4 += 4) {
        const float4 a0 = *(const float4*)&S1R[(x0 + 0) * RS + k4];
        const float4 a1 = *(const float4*)&S1R[(x0 + 1) * RS + k4];
        const float4 a2 = *(const float4*)&S1R[(x0 + 2) * RS + k4];
        const float2 b0 = *(const float2*)&H2[(k4 + 0) * NN + y0];
        const float2 b1 = *(const float2*)&H2[(k4 + 1) * NN + y0];
        const float2 b2 = *(const float2*)&H2[(k4 + 2) * NN + y0];
        const float2 b3 = *(const float2*)&H2[(k4 + 3) * NN + y0];
        const float av[3][4] = {{a0.x, a0.y, a0.z, a0.w},
                                {a1.x, a1.y, a1.z, a1.w},
                                {a2.x, a2.y, a2.z, a2.w}};
        const float bv[4][2] = {{b0.x, b0.y}, {b1.x, b1.y},
                                {b2.x, b2.y}, {b3.x, b3.y}};
        #pragma unroll
        for (int jx = 0; jx < 3; ++jx)
            #pragma unroll
            for (int jy = 0; jy < 2; ++jy) {
                const float s0 = av[jx][0] + bv[0][jy];
                const float s1 = av[jx][1] + bv[1][jy];
                const float s2 = av[jx][2] + bv[2][jy];
                const float s3 = av[jx][3] + bv[3][jy];
                acc2[jx][jy] = fmaxf(acc2[jx][jy], fmaxf(s0, s1));
                acc2[jx][jy] = fmaxf(acc2[jx][jy], fmaxf(s2, s3));
            }
    }

    const float wgt = weights[c];
    float* outp = sw + (size_t)bc * PP + (size_t)x0r * NN;
    #pragma unroll
    for (int jx = 0; jx < 3; ++jx) {
        float2 o;
        o.x = __expf(acc2[jx][0]) * wgt;
        o.y = __expf(acc2[jx][1]) * wgt;
        *(float2*)&outp[(x0 + jx) * NN + y0] = o;
    }
}

// ---------------------------------------------------------------------------
// Kernel 2: combine. 2 threads per (b,x,y) — each handles 8 triples.
// All sw reads fully coalesced within each wave; mask/out via int4/float4.
// ---------------------------------------------------------------------------
__global__ __launch_bounds__(256) void combine_kernel(
    const float* __restrict__ sw,      // [B,Nc,N,N]
    const int*   __restrict__ mask,    // [B,N,N,R]
    const float* __restrict__ biases,  // [R]
    float*       __restrict__ out)     // [B,N,N,R]
{
    const int tq = threadIdx.x >> 7;                       // t-half 0/1
    const int pl = blockIdx.x * 128 + (threadIdx.x & 127); // (b,p) linear
    if (pl >= BB * PP) return;
    const int b = pl / PP;
    const int p = pl - b * PP;

    const float* base = sw + (size_t)b * NC * PP + p;

    float acc[8];
    #pragma unroll
    for (int tt = 0; tt < 8; ++tt) {
        const int t = tq * 8 + tt;
        float s = biases[t];
        #pragma unroll
        for (int i = 0; i < NI; ++i)
            s += base[(size_t)(t * NI + i) * PP];
        acc[tt] = s;
    }

    const int4* m4 = (const int4*)(mask + (size_t)pl * RR + tq * 8);
    float4*     o4 = (float4*)(out + (size_t)pl * RR + tq * 8);
    #pragma unroll
    for (int q = 0; q < 2; ++q) {
        const int4 m = m4[q];
        float4 o;
        o.x = (m.x == 0) ? acc[q * 4 + 0] : NEG;
        o.y = (m.y == 0) ? acc[q * 4 + 1] : NEG;
        o.z = (m.z == 0) ? acc[q * 4 + 2] : NEG;
        o.w = (m.w == 0) ? acc[q * 4 + 3] : NEG;
        o4[q] = o;
    }
}

extern "C" void kernel_launch(void* const* d_in, const int* in_sizes, int n_in,
                              void* d_out, int out_size, void* d_ws, size_t ws_size,
                              hipStream_t stream)
{
    const float* trans   = (const float*)d_in[0];  // [B,N,N,T] f32
    const int*   mask    = (const int*)  d_in[1];  // [B,N,N,R] i32
    const int*   rules   = (const int*)  d_in[2];  // [Nc,3]    i32
    const float* weights = (const float*)d_in[3];  // [Nt,Ni]   f32
    const float* biases  = (const float*)d_in[4];  // [Nt]      f32
    float* out = (float*)d_out;

    float* tpose = (float*)d_ws;                   // [B,33,2304] = 1.22 MB
    float* sw    = tpose + (size_t)BB * TT * PP;   // [B,Nc,48,48] = 2.95 MB

    transpose_kernel<<<BB * 36, 256, 0, stream>>>(trans, tpose);

    chain_dp_kernel<<<BB * NC * 2, 192, 0, stream>>>(tpose, rules, weights, sw);

    const int total2 = BB * PP * 2;                // 2 threads per (b,p)
    combine_kernel<<<(total2 + 255) / 256, 256, 0, stream>>>(sw, mask, biases, out);
}